// Round 4
// baseline (276672.290 us; speedup 1.0000x reference)
//
#include <hip/hip_runtime.h>
#include <math.h>

// DeepAR point forecast, persistent kernel v3.
// vs v2: 1024-thr blocks (16 waves/CU, 50% occ), h in [sample][k] layout with
// interleaved chunking + float4 loads (full line utilization), conflict-free
// LDS weight layout, spread-counter barrier with master-release flag,
// x-features distributed across k-lanes ("extra k" trick).
//
// Thread layout: 1024 thr = 16 waves. lane l: si2 = l&3, c = l>>2 (16 chunks).
// Thread samples: s0 = w*4+si2, s1 = s0+64. Chunk c owns k = {i*64 + c*4 + j}.
// Butterfly allreduce over c (shfl_xor 4,8,16,32) -> every lane has full gate
// preacts for its 2 samples; c-state kept redundantly on all lanes (bitwise
// deterministic); c==0 lanes write h.
//
// Coherence: all inter-block data written with agent-scope atomic stores
// (through to MALL); barrier = vmcnt(0) + spread atomicAdd + master sums 16
// counters -> release flag; acquire fence (INV) after. (proven in v2)
//
// Decoder lag semantics (verified vs reference buf-shift): lag L at step t
// reads V[28+t-L] if t-L<720 else prediction Yhat[t-L-1].
// pad_mask all-True -> scale = mean |target| over 720-step context.

#define CTXL   720
#define MAXLAG 28
#define TT0    916
#define NSTEP  887
#define OUTW   887
#define HSB    (128 * 512)   // one h buffer: [128 samples][512 units]

struct Prm {
  const float *Wih0, *Whh0, *bih0, *bhh0;
  const float *Wih1, *Whh1, *bih1, *bhh1;
  const float *Whead, *bhead;
  const float *scale, *ls, *V, *embf;
  float *Yhat, *H0, *H1, *Ypart, *out;
  int *bar;   // [16 counters @ stride 16] + rel @ [256]
};

__device__ __forceinline__ void stb(float* p, float v) {
  __hip_atomic_store(p, v, __ATOMIC_RELAXED, __HIP_MEMORY_SCOPE_AGENT);
}
__device__ __forceinline__ float sigm(float x) {
  return __builtin_amdgcn_rcpf(1.f + __expf(-x));
}
__device__ __forceinline__ float tanh_f(float x) {
  return fmaf(2.f, __builtin_amdgcn_rcpf(1.f + __expf(-2.f * x)), -1.f);
}

__global__ void prep_kernel(const float* __restrict__ X, const float* __restrict__ emb,
                            float* __restrict__ scale, float* __restrict__ ls,
                            float* __restrict__ V, float* __restrict__ embf,
                            float* __restrict__ zb /*4*HSB*/, int* __restrict__ bar)
{
    const int bid = blockIdx.x, tid = threadIdx.x;
    if (bid < 128) {
        const int b = bid;
        __shared__ float sred[256];
        __shared__ float s_scale;
        float p = 0.f;
        for (int t = tid; t < CTXL; t += 256)
            p += fabsf(X[(size_t)(b * TT0 + MAXLAG + t) * 2]);
        sred[tid] = p; __syncthreads();
        for (int s = 128; s > 0; s >>= 1) {
            if (tid < s) sred[tid] += sred[tid + s];
            __syncthreads();
        }
        if (tid == 0) {
            float sc = fmaxf(sred[0] / (float)CTXL, 1e-10f);
            s_scale = sc; scale[b] = sc; ls[b] = logf(sc);
        }
        __syncthreads();
        const float sc = s_scale;
        for (int j = tid; j < TT0 - 168; j += 256)
            V[(size_t)j * 128 + b] = X[(size_t)(b * TT0 + j) * 2] / sc;
        for (int t = tid; t < NSTEP; t += 256) {
            int cc = (int)X[(size_t)(b * TT0 + MAXLAG + t) * 2 + 1];
            #pragma unroll
            for (int d = 0; d < 5; ++d)
                embf[((size_t)t * 5 + d) * 128 + b] = emb[cc * 5 + d];
        }
    } else {
        const int ZT = 4 * HSB;
        for (int idx = (bid - 128) * 256 + tid; idx < ZT; idx += 128 * 256)
            zb[idx] = 0.f;
        if (bid == 128 && tid < 272) bar[tid] = 0;
    }
}

__global__ __launch_bounds__(1024, 1) void deepar_persist(Prm p)
{
    const int tid = threadIdx.x, blk = blockIdx.x;
    const int l = tid & 63, w = tid >> 6;
    const int si2 = l & 3, c = l >> 2;       // c: k-chunk 0..15
    const int s0 = w * 4 + si2, s1 = s0 + 64;
    const int u0 = 2 * blk;

    // sW[m][r]: row of 544 dwords; (i,c,j) at i*68 + c*4 + j  (k = i*64 + c*4 + j)
    __shared__ float sW[3][8][544];
    __shared__ float sX0[8][17];
    __shared__ float sB0[8], sB1[8], sHead[2];

    for (int idx = tid; idx < 3072; idx += 1024) {
        const int m = idx >> 10, rem = idx & 1023;
        const int r = rem >> 7, rem2 = rem & 127;
        const int i = rem2 >> 4, cc = rem2 & 15;
        const int grow = ((r & 3) << 9) + u0 + (r >> 2);
        const float* W = (m == 0) ? p.Whh0 : (m == 1) ? p.Wih1 : p.Whh1;
        *(float4*)&sW[m][r][i * 68 + cc * 4] =
            *(const float4*)&W[(size_t)grow * 512 + i * 64 + cc * 4];
    }
    if (tid < 136) {
        const int r = tid / 17, j = tid % 17;
        sX0[r][j] = p.Wih0[(((r & 3) << 9) + u0 + (r >> 2)) * 17 + j];
    }
    if (tid < 8) {
        const int grow = ((tid & 3) << 9) + u0 + (tid >> 2);
        sB0[tid] = p.bih0[grow] + p.bhh0[grow];
        sB1[tid] = p.bih1[grow] + p.bhh1[grow];
    }
    if (tid < 2) sHead[tid] = p.Whead[u0 + tid];
    __syncthreads();

    const float bheadv = p.bhead[0];
    const float lsv0 = p.ls[s0], lsv1 = p.ls[s1];
    const float scl0 = p.scale[s0], scl1 = p.scale[s1];
    float c0r[2][2] = {{0.f,0.f},{0.f,0.f}}, c1r[2][2] = {{0.f,0.f},{0.f,0.f}};
    float hh[2][2];
    int ph = 0;
    int* ctr = p.bar;
    int* rel = p.bar + 256;

    auto gbar = [&]() {
        asm volatile("s_waitcnt vmcnt(0)" ::: "memory");
        __syncthreads();
        ++ph;
        if (tid == 0)
            __hip_atomic_fetch_add(&ctr[(blk & 15) * 16], 1,
                                   __ATOMIC_RELAXED, __HIP_MEMORY_SCOPE_AGENT);
        if (blk == 0) {
            if (tid < 64) {
                const int target = 256 * ph;
                for (;;) {
                    int v = (l < 16) ? __hip_atomic_load(&ctr[l * 16], __ATOMIC_RELAXED,
                                                         __HIP_MEMORY_SCOPE_AGENT) : 0;
                    v += __shfl_xor(v, 1, 64); v += __shfl_xor(v, 2, 64);
                    v += __shfl_xor(v, 4, 64); v += __shfl_xor(v, 8, 64);
                    if (__shfl(v, 0, 64) >= target) break;
                    __builtin_amdgcn_s_sleep(1);
                }
                if (tid == 0)
                    __hip_atomic_store(rel, ph, __ATOMIC_RELAXED, __HIP_MEMORY_SCOPE_AGENT);
            }
        } else if (tid == 0) {
            while (__hip_atomic_load(rel, __ATOMIC_RELAXED, __HIP_MEMORY_SCOPE_AGENT) < ph)
                __builtin_amdgcn_s_sleep(1);
        }
        __syncthreads();
        __builtin_amdgcn_fence(__ATOMIC_ACQUIRE, "agent");
    };

    auto bf4 = [&](float& v) {
        v += __shfl_xor(v, 4, 64);  v += __shfl_xor(v, 8, 64);
        v += __shfl_xor(v, 16, 64); v += __shfl_xor(v, 32, 64);
    };

    // single-matrix matmul: acc[r][j] += sum_k W[m][r][k] * h_j[k]  (this lane's chunk)
    auto mm2 = [&](const float* hA, const float* hB, int m, float (&acc)[8][2]) {
        const float* Wb = &sW[m][0][0] + c * 4;
        #pragma unroll
        for (int i = 0; i < 8; ++i) {
            const float4 a = *(const float4*)(hA + i * 64 + c * 4);
            const float4 b = *(const float4*)(hB + i * 64 + c * 4);
            #pragma unroll
            for (int r = 0; r < 8; ++r) {
                const float4 wv = *(const float4*)(Wb + r * 544 + i * 68);
                acc[r][0] = fmaf(wv.x, a.x, fmaf(wv.y, a.y, fmaf(wv.z, a.z, fmaf(wv.w, a.w, acc[r][0]))));
                acc[r][1] = fmaf(wv.x, b.x, fmaf(wv.y, b.y, fmaf(wv.z, b.z, fmaf(wv.w, b.w, acc[r][1]))));
            }
        }
    };
    // fused dual-matrix (m=0 -> a0, m=1 -> a1) sharing the same h loads
    auto mmCtx = [&](const float* hA, const float* hB, float (&a0)[8][2], float (&a1)[8][2]) {
        const float* W0 = &sW[0][0][0] + c * 4;
        const float* W1 = &sW[1][0][0] + c * 4;
        #pragma unroll
        for (int i = 0; i < 8; ++i) {
            const float4 a = *(const float4*)(hA + i * 64 + c * 4);
            const float4 b = *(const float4*)(hB + i * 64 + c * 4);
            #pragma unroll
            for (int r = 0; r < 8; ++r) {
                const float4 w0 = *(const float4*)(W0 + r * 544 + i * 68);
                a0[r][0] = fmaf(w0.x, a.x, fmaf(w0.y, a.y, fmaf(w0.z, a.z, fmaf(w0.w, a.w, a0[r][0]))));
                a0[r][1] = fmaf(w0.x, b.x, fmaf(w0.y, b.y, fmaf(w0.z, b.z, fmaf(w0.w, b.w, a0[r][1]))));
                const float4 w1 = *(const float4*)(W1 + r * 544 + i * 68);
                a1[r][0] = fmaf(w1.x, a.x, fmaf(w1.y, a.y, fmaf(w1.z, a.z, fmaf(w1.w, a.w, a1[r][0]))));
                a1[r][1] = fmaf(w1.x, b.x, fmaf(w1.y, b.y, fmaf(w1.z, b.z, fmaf(w1.w, b.w, a1[r][1]))));
            }
        }
    };

    // x-part: feature j = c (+ j=16 on c==0). xa0/xa1 are this lane's feature values.
    auto xpart = [&](int t, float y0, float y1, bool dec, float (&a0)[8][2]) {
        float xa0, xa1;
        if (c == 0) { xa0 = y0; xa1 = y1; }
        else if (c <= 10) {
            const int lag = (c <= 7) ? c : (c - 6) * 7;   // 1..7,14,21,28
            const int u = t - lag;
            if (!dec || u < CTXL) {
                xa0 = p.V[(size_t)(MAXLAG + u) * 128 + s0];
                xa1 = p.V[(size_t)(MAXLAG + u) * 128 + s1];
            } else {
                xa0 = p.Yhat[(size_t)(u - 1) * 128 + s0];
                xa1 = p.Yhat[(size_t)(u - 1) * 128 + s1];
            }
        } else if (c == 11) { xa0 = lsv0; xa1 = lsv1; }
        else {
            xa0 = p.embf[((size_t)t * 5 + (c - 12)) * 128 + s0];
            xa1 = p.embf[((size_t)t * 5 + (c - 12)) * 128 + s1];
        }
        #pragma unroll
        for (int r = 0; r < 8; ++r) {
            const float wj = sX0[r][c];
            a0[r][0] = fmaf(wj, xa0, a0[r][0]);
            a0[r][1] = fmaf(wj, xa1, a0[r][1]);
        }
        if (c == 0) {
            const float xb0 = p.embf[((size_t)t * 5 + 4) * 128 + s0];
            const float xb1 = p.embf[((size_t)t * 5 + 4) * 128 + s1];
            #pragma unroll
            for (int r = 0; r < 8; ++r) {
                const float w16 = sX0[r][16];
                a0[r][0] = fmaf(w16, xb0, a0[r][0]);
                a0[r][1] = fmaf(w16, xb1, a0[r][1]);
            }
        }
    };

    auto l0gates = [&](float (&a0)[8][2], float* H0n) {
        #pragma unroll
        for (int e = 0; e < 2; ++e)
            #pragma unroll
            for (int j = 0; j < 2; ++j) {
                const float ig = sigm(a0[e*4+0][j] + sB0[e*4+0]);
                const float fg = sigm(a0[e*4+1][j] + sB0[e*4+1]);
                const float gt = tanh_f(a0[e*4+2][j] + sB0[e*4+2]);
                const float og = sigm(a0[e*4+3][j] + sB0[e*4+3]);
                c0r[e][j] = fg * c0r[e][j] + ig * gt;
                hh[e][j] = og * tanh_f(c0r[e][j]);
            }
        if (c == 0) {
            stb(&H0n[(size_t)s0 * 512 + u0],     hh[0][0]);
            stb(&H0n[(size_t)s0 * 512 + u0 + 1], hh[1][0]);
            stb(&H0n[(size_t)s1 * 512 + u0],     hh[0][1]);
            stb(&H0n[(size_t)s1 * 512 + u0 + 1], hh[1][1]);
        }
    };
    auto l1gates = [&](float (&a1)[8][2], float* H1n, int par) {
        #pragma unroll
        for (int e = 0; e < 2; ++e)
            #pragma unroll
            for (int j = 0; j < 2; ++j) {
                const float ig = sigm(a1[e*4+0][j] + sB1[e*4+0]);
                const float fg = sigm(a1[e*4+1][j] + sB1[e*4+1]);
                const float gt = tanh_f(a1[e*4+2][j] + sB1[e*4+2]);
                const float og = sigm(a1[e*4+3][j] + sB1[e*4+3]);
                c1r[e][j] = fg * c1r[e][j] + ig * gt;
                hh[e][j] = og * tanh_f(c1r[e][j]);
            }
        if (c == 0) {
            stb(&H1n[(size_t)s0 * 512 + u0],     hh[0][0]);
            stb(&H1n[(size_t)s0 * 512 + u0 + 1], hh[1][0]);
            stb(&H1n[(size_t)s1 * 512 + u0],     hh[0][1]);
            stb(&H1n[(size_t)s1 * 512 + u0 + 1], hh[1][1]);
            stb(&p.Ypart[(size_t)par * 32768 + s0 * 256 + blk],
                sHead[0] * hh[0][0] + sHead[1] * hh[1][0]);
            stb(&p.Ypart[(size_t)par * 32768 + s1 * 256 + blk],
                sHead[0] * hh[0][1] + sHead[1] * hh[1][1]);
        }
    };

    // ======================= CONTEXT: P = 0..720 =======================
    for (int P = 0; P <= CTXL; ++P) {
        // lazy out-write for step P-2 (block b < 128 handles sample b)
        if (P >= 2 && blk < 128 && tid < 64) {
            const float4 v4 = *((const float4*)&p.Ypart[(size_t)(P & 1) * 32768 + blk * 256] + l);
            float vs = (v4.x + v4.y) + (v4.z + v4.w);
            vs += __shfl_xor(vs, 1, 64);  vs += __shfl_xor(vs, 2, 64);
            vs += __shfl_xor(vs, 4, 64);  vs += __shfl_xor(vs, 8, 64);
            vs += __shfl_xor(vs, 16, 64); vs += __shfl_xor(vs, 32, 64);
            if (l == 0)
                stb(&p.out[(size_t)blk * OUTW + (P - 2)], (vs + bheadv) * p.scale[blk]);
        }

        float a0[8][2] = {}, a1[8][2] = {};
        const float* H0p = p.H0 + (size_t)((P - 1) & 1) * HSB;
        mmCtx(H0p + (size_t)s0 * 512, H0p + (size_t)s1 * 512, a0, a1);
        const float* H1p = p.H1 + (size_t)(P & 1) * HSB;
        mm2(H1p + (size_t)s0 * 512, H1p + (size_t)s1 * 512, 2, a1);

        if (P < CTXL) {
            const float y0 = p.V[(size_t)(MAXLAG + P) * 128 + s0];
            const float y1 = p.V[(size_t)(MAXLAG + P) * 128 + s1];
            xpart(P, y0, y1, false, a0);
        }
        #pragma unroll
        for (int r = 0; r < 8; ++r) {
            bf4(a0[r][0]); bf4(a0[r][1]);
            bf4(a1[r][0]); bf4(a1[r][1]);
        }
        if (P < CTXL) l0gates(a0, p.H0 + (size_t)(P & 1) * HSB);
        if (P >= 1)   l1gates(a1, p.H1 + (size_t)((P - 1) & 1) * HSB, (P - 1) & 1);
        gbar();
    }

    // ======================= DECODE: t = 720..886 =======================
    for (int t = CTXL; t < NSTEP; ++t) {
        // ---- phase A: y(t-1) + L0(t) ----
        {
            const float* yp = p.Ypart + (size_t)((t - 1) & 1) * 32768;
            float ys0 = 0.f, ys1 = 0.f;
            #pragma unroll
            for (int i = 0; i < 4; ++i) {
                const float4 v = *(const float4*)&yp[(size_t)s0 * 256 + c * 16 + i * 4];
                ys0 += (v.x + v.y) + (v.z + v.w);
                const float4 u = *(const float4*)&yp[(size_t)s1 * 256 + c * 16 + i * 4];
                ys1 += (u.x + u.y) + (u.z + u.w);
            }
            bf4(ys0); bf4(ys1);
            ys0 += bheadv; ys1 += bheadv;
            if (blk == 0 && c == 0) {
                stb(&p.Yhat[(size_t)(t - 1) * 128 + s0], ys0);
                stb(&p.Yhat[(size_t)(t - 1) * 128 + s1], ys1);
                stb(&p.out[(size_t)s0 * OUTW + (t - 1)], ys0 * scl0);
                stb(&p.out[(size_t)s1 * OUTW + (t - 1)], ys1 * scl1);
            }
            float a0[8][2] = {};
            const float* H0p = p.H0 + (size_t)((t - 1) & 1) * HSB;
            mm2(H0p + (size_t)s0 * 512, H0p + (size_t)s1 * 512, 0, a0);
            xpart(t, ys0, ys1, true, a0);
            #pragma unroll
            for (int r = 0; r < 8; ++r) { bf4(a0[r][0]); bf4(a0[r][1]); }
            l0gates(a0, p.H0 + (size_t)(t & 1) * HSB);
            gbar();
        }
        // ---- phase B: L1(t) ----
        {
            float a1[8][2] = {};
            const float* H0c = p.H0 + (size_t)(t & 1) * HSB;
            mm2(H0c + (size_t)s0 * 512, H0c + (size_t)s1 * 512, 1, a1);
            const float* H1p = p.H1 + (size_t)((t - 1) & 1) * HSB;
            mm2(H1p + (size_t)s0 * 512, H1p + (size_t)s1 * 512, 2, a1);
            #pragma unroll
            for (int r = 0; r < 8; ++r) { bf4(a1[r][0]); bf4(a1[r][1]); }
            l1gates(a1, p.H1 + (size_t)(t & 1) * HSB, t & 1);
            gbar();
        }
    }

    // ---- tail: out[:, 886] (block 0) ----
    if (blk == 0) {
        const float* yp = p.Ypart + (size_t)((NSTEP - 1) & 1) * 32768;
        float ys0 = 0.f, ys1 = 0.f;
        #pragma unroll
        for (int i = 0; i < 4; ++i) {
            const float4 v = *(const float4*)&yp[(size_t)s0 * 256 + c * 16 + i * 4];
            ys0 += (v.x + v.y) + (v.z + v.w);
            const float4 u = *(const float4*)&yp[(size_t)s1 * 256 + c * 16 + i * 4];
            ys1 += (u.x + u.y) + (u.z + u.w);
        }
        bf4(ys0); bf4(ys1);
        if (c == 0) {
            stb(&p.out[(size_t)s0 * OUTW + (NSTEP - 1)], (ys0 + bheadv) * scl0);
            stb(&p.out[(size_t)s1 * OUTW + (NSTEP - 1)], (ys1 + bheadv) * scl1);
        }
    }
}

extern "C" void kernel_launch(void* const* d_in, const int* in_sizes, int n_in,
                              void* d_out, int out_size, void* d_ws, size_t ws_size,
                              hipStream_t stream)
{
    (void)in_sizes; (void)n_in; (void)out_size; (void)ws_size;
    const float* X     = (const float*)d_in[0];
    // d_in[1] = pad_mask (all True; see header)
    const float* emb   = (const float*)d_in[2];
    Prm prm;
    prm.Wih0 = (const float*)d_in[3];
    prm.Whh0 = (const float*)d_in[4];
    prm.bih0 = (const float*)d_in[5];
    prm.bhh0 = (const float*)d_in[6];
    prm.Wih1 = (const float*)d_in[7];
    prm.Whh1 = (const float*)d_in[8];
    prm.bih1 = (const float*)d_in[9];
    prm.bhh1 = (const float*)d_in[10];
    prm.Whead = (const float*)d_in[11];
    prm.bhead = (const float*)d_in[12];
    float* out = (float*)d_out;

    float* ws    = (float*)d_ws;
    float* scale = ws;                            // 128
    float* ls    = scale + 128;                   // 128
    float* V     = ls + 128;                      // 748*128
    float* embf  = V + 748 * 128;                 // 887*5*128
    float* Yhat  = embf + (size_t)888 * 5 * 128;  // 888*128
    float* H0    = Yhat + 888 * 128;              // 2*HSB
    float* H1    = H0 + 2 * HSB;                  // 2*HSB
    float* Ypart = H1 + 2 * HSB;                  // 2*128*256
    int*   bar   = (int*)(Ypart + 2 * 128 * 256); // 272 ints

    hipLaunchKernelGGL(prep_kernel, dim3(256), dim3(256), 0, stream,
                       X, emb, scale, ls, V, embf, H0, bar);

    prm.scale = scale; prm.ls = ls; prm.V = V; prm.embf = embf;
    prm.Yhat = Yhat; prm.H0 = H0; prm.H1 = H1; prm.Ypart = Ypart; prm.out = out;
    prm.bar = bar;

    void* args[] = { &prm };
    hipLaunchCooperativeKernel((void*)deepar_persist, dim3(256), dim3(1024),
                               args, 0, stream);
}

// Round 5
// 45617.032 us; speedup vs baseline: 6.0651x; 6.0651x over previous
//
#include <hip/hip_runtime.h>
#include <math.h>

// DeepAR point forecast, persistent kernel v4 (= v2 structure + targeted fixes).
// vs v2 (42.8ms): h state in [k/4][sample][4] layout -> dwordx4 h loads (4x fewer
// load instrs), chunk-padded LDS weights (conflict-free b128), spread-counter
// barrier (16 counters, all-blocks poll via lane<16 + shfl reduce).
// vs v3 (regression): back to 512 threads, NO array-ref lambdas (macros with
// block-scoped locals) -- v3's 276ms was scratch-spill thrash (VGPR 64,
// FETCH+WRITE 742GB symmetric).
//
// Thread layout: 512 thr = 8 waves. lane l: si = l&15 (sample-in-wave),
// c = l>>4 (k-chunk, 128 k each). s = w*16+si. Each thread: 1 sample, its
// 128-k chunk, all 8 gate rows of the block's 2 hidden units. Butterfly
// shfl_xor(16,32) -> full gate preacts on every lane; c-state in registers
// (4 redundant lane copies, bitwise deterministic); c==0 lanes write h (8B).
//
// Coherence (proven v2): all inter-block data written with agent-scope atomic
// stores (write-through to MALL; L2 never dirty). Barrier: vmcnt(0) +
// syncthreads + spread atomicAdd + wave0 polls 16 counters + acquire-INV.
//
// Decoder lag semantics (verified vs reference buf-shift): lag L at step t
// reads V[28+t-L] if t-L<720 else prediction Yhat[t-L-1].
// pad_mask all-True -> scale = mean |target| over 720-step context.

#define CTXL   720
#define MAXLAG 28
#define TT0    916
#define NSTEP  887
#define OUTW   887
#define HSB    (128 * 512)   // one h buffer: [128 k4][128 samples][4]

struct Prm {
  const float *Wih0, *Whh0, *bih0, *bhh0;
  const float *Wih1, *Whh1, *bih1, *bhh1;
  const float *Whead, *bhead;
  const float *scale, *ls, *V, *embf;
  float *Yhat, *H0, *H1, *Ypart, *out;
  int *bar;   // 16 counters at stride 16 (indices 0,16,..,240)
};

__device__ __forceinline__ void stb(float* p, float v) {
  __hip_atomic_store(p, v, __ATOMIC_RELAXED, __HIP_MEMORY_SCOPE_AGENT);
}
__device__ __forceinline__ void stb2(float* p, float a, float b) {
  union { float2 f; unsigned long long u; } cv;
  cv.f = make_float2(a, b);
  __hip_atomic_store((unsigned long long*)p, cv.u, __ATOMIC_RELAXED,
                     __HIP_MEMORY_SCOPE_AGENT);
}
__device__ __forceinline__ float sigm(float x) {
  return __builtin_amdgcn_rcpf(1.f + __expf(-x));
}
__device__ __forceinline__ float tanh_f(float x) {
  return fmaf(2.f, __builtin_amdgcn_rcpf(1.f + __expf(-2.f * x)), -1.f);
}

__global__ void prep_kernel(const float* __restrict__ X, const float* __restrict__ emb,
                            float* __restrict__ scale, float* __restrict__ ls,
                            float* __restrict__ V, float* __restrict__ embf,
                            float* __restrict__ zb /*4*HSB*/, int* __restrict__ bar)
{
    const int bid = blockIdx.x, tid = threadIdx.x;
    if (bid < 128) {
        const int b = bid;
        __shared__ float sred[256];
        __shared__ float s_scale;
        float p = 0.f;
        for (int t = tid; t < CTXL; t += 256)
            p += fabsf(X[(size_t)(b * TT0 + MAXLAG + t) * 2]);
        sred[tid] = p; __syncthreads();
        for (int s = 128; s > 0; s >>= 1) {
            if (tid < s) sred[tid] += sred[tid + s];
            __syncthreads();
        }
        if (tid == 0) {
            float sc = fmaxf(sred[0] / (float)CTXL, 1e-10f);
            s_scale = sc; scale[b] = sc; ls[b] = logf(sc);
        }
        __syncthreads();
        const float sc = s_scale;
        for (int j = tid; j < TT0 - 168; j += 256)
            V[(size_t)j * 128 + b] = X[(size_t)(b * TT0 + j) * 2] / sc;
        for (int t = tid; t < NSTEP; t += 256) {
            int cc = (int)X[(size_t)(b * TT0 + MAXLAG + t) * 2 + 1];
            #pragma unroll
            for (int d = 0; d < 5; ++d)
                embf[((size_t)t * 5 + d) * 128 + b] = emb[cc * 5 + d];
        }
    } else {
        const int ZT = 4 * HSB;
        for (int idx = (bid - 128) * 256 + tid; idx < ZT; idx += 128 * 256)
            zb[idx] = 0.f;
        if (bid == 128) bar[tid] = 0;
    }
}

// h-load + FMA over this thread's 128-k chunk, 8 rows. ACC must be float[8].
#define MM_ONE(HBASE, SW, ACC) {                                              \
    const float* hb_ = (HBASE) + (size_t)c * (32 * 512) + s * 4;              \
    const float* wb_ = &(SW)[0][0] + c * 136;                                 \
    _Pragma("unroll")                                                         \
    for (int mb_ = 0; mb_ < 4; ++mb_) {                                       \
        float4 hv_[8];                                                        \
        _Pragma("unroll")                                                     \
        for (int j_ = 0; j_ < 8; ++j_)                                        \
            hv_[j_] = *(const float4*)(hb_ + (mb_ * 8 + j_) * 512);           \
        _Pragma("unroll")                                                     \
        for (int r_ = 0; r_ < 8; ++r_) {                                      \
            _Pragma("unroll")                                                 \
            for (int j_ = 0; j_ < 8; ++j_) {                                  \
                const float4 wv_ = *(const float4*)(wb_ + r_ * 544 + (mb_ * 8 + j_) * 4); \
                ACC[r_] = fmaf(wv_.x, hv_[j_].x, fmaf(wv_.y, hv_[j_].y,       \
                          fmaf(wv_.z, hv_[j_].z, fmaf(wv_.w, hv_[j_].w, ACC[r_])))); \
            }                                                                 \
        }                                                                     \
    } }

// dual-matrix version sharing h loads (context: Whh0->ACCA, Wih1->ACCB)
#define MM_DUAL(HBASE, SWA, SWB, ACCA, ACCB) {                                \
    const float* hb_ = (HBASE) + (size_t)c * (32 * 512) + s * 4;              \
    const float* wa_ = &(SWA)[0][0] + c * 136;                                \
    const float* wc_ = &(SWB)[0][0] + c * 136;                                \
    _Pragma("unroll")                                                         \
    for (int mb_ = 0; mb_ < 4; ++mb_) {                                       \
        float4 hv_[8];                                                        \
        _Pragma("unroll")                                                     \
        for (int j_ = 0; j_ < 8; ++j_)                                        \
            hv_[j_] = *(const float4*)(hb_ + (mb_ * 8 + j_) * 512);           \
        _Pragma("unroll")                                                     \
        for (int r_ = 0; r_ < 8; ++r_) {                                      \
            _Pragma("unroll")                                                 \
            for (int j_ = 0; j_ < 8; ++j_) {                                  \
                const float4 wv_ = *(const float4*)(wa_ + r_ * 544 + (mb_ * 8 + j_) * 4); \
                ACCA[r_] = fmaf(wv_.x, hv_[j_].x, fmaf(wv_.y, hv_[j_].y,      \
                           fmaf(wv_.z, hv_[j_].z, fmaf(wv_.w, hv_[j_].w, ACCA[r_])))); \
                const float4 wu_ = *(const float4*)(wc_ + r_ * 544 + (mb_ * 8 + j_) * 4); \
                ACCB[r_] = fmaf(wu_.x, hv_[j_].x, fmaf(wu_.y, hv_[j_].y,      \
                           fmaf(wu_.z, hv_[j_].z, fmaf(wu_.w, hv_[j_].w, ACCB[r_])))); \
            }                                                                 \
        }                                                                     \
    } }

#define BFLY8(ACC) {                                                          \
    _Pragma("unroll")                                                         \
    for (int r_ = 0; r_ < 8; ++r_) {                                          \
        ACC[r_] += __shfl_xor(ACC[r_], 16, 64);                               \
        ACC[r_] += __shfl_xor(ACC[r_], 32, 64);                               \
    } }

// x-part (bias included), added post-butterfly on ALL lanes (uniform).
#define XPART(T, Y0, DEC, ACC) {                                              \
    float xf[17];                                                             \
    xf[0] = (Y0);                                                             \
    _Pragma("unroll")                                                         \
    for (int j_ = 0; j_ < 10; ++j_) {                                         \
        const int u_ = (T) - LG[j_];                                          \
        xf[1 + j_] = (!(DEC) || u_ < CTXL)                                    \
            ? p.V[(size_t)(MAXLAG + u_) * 128 + s]                            \
            : p.Yhat[(size_t)(u_ - 1) * 128 + s];                             \
    }                                                                         \
    xf[11] = lsv;                                                             \
    _Pragma("unroll")                                                         \
    for (int d_ = 0; d_ < 5; ++d_)                                            \
        xf[12 + d_] = p.embf[((size_t)(T) * 5 + d_) * 128 + s];               \
    _Pragma("unroll")                                                         \
    for (int r_ = 0; r_ < 8; ++r_) {                                          \
        float xd_ = sB0[r_];                                                  \
        _Pragma("unroll")                                                     \
        for (int j_ = 0; j_ < 17; ++j_) xd_ = fmaf(sX0[r_][j_], xf[j_], xd_); \
        ACC[r_] += xd_;                                                       \
    } }

__global__ __launch_bounds__(512, 2) void deepar_persist(Prm p)
{
    const int tid = threadIdx.x, blk = blockIdx.x;
    const int l = tid & 63, w = tid >> 6;
    const int si = l & 15, c = l >> 4;     // sample-in-wave, k-chunk 0..3
    const int s = w * 16 + si;             // sample 0..127
    const int u0 = 2 * blk;

    // sW[m][r][c*136 + kk] = W_m[row(r)][c*128 + kk]; row stride 544 (pad 12)
    __shared__ float sW[3][8][544];
    __shared__ float sX0[8][17];
    __shared__ float sB0[8], sB1[8], sHead[2];
    __shared__ float sPY[4][128];
    __shared__ float sRed[32][16];

    for (int idx = tid; idx < 3072; idx += 512) {
        const int m = idx >> 10, rem = idx & 1023;
        const int r = rem >> 7, k = (rem & 127) * 4;
        const int cc = k >> 7, kk = k & 127;
        const int grow = ((r & 3) << 9) + u0 + (r >> 2);
        const float* W = (m == 0) ? p.Whh0 : (m == 1) ? p.Wih1 : p.Whh1;
        *(float4*)&sW[m][r][cc * 136 + kk] = *(const float4*)&W[(size_t)grow * 512 + k];
    }
    if (tid < 136) {
        const int r = tid / 17, j = tid % 17;
        sX0[r][j] = p.Wih0[(((r & 3) << 9) + u0 + (r >> 2)) * 17 + j];
    }
    if (tid < 8) {
        const int grow = ((tid & 3) << 9) + u0 + (tid >> 2);
        sB0[tid] = p.bih0[grow] + p.bhh0[grow];
        sB1[tid] = p.bih1[grow] + p.bhh1[grow];
    }
    if (tid < 2) sHead[tid] = p.Whead[u0 + tid];
    __syncthreads();

    const float bheadv = p.bhead[0];
    const float lsv = p.ls[s];
    const float scl = p.scale[s];
    float c0r[2] = {0.f, 0.f}, c1r[2] = {0.f, 0.f};
    int ph = 0;
    int* ctr = p.bar;
    const int LG[10] = {1, 2, 3, 4, 5, 6, 7, 14, 21, 28};

    auto gbar = [&]() {
        asm volatile("s_waitcnt vmcnt(0)" ::: "memory");
        __syncthreads();
        ++ph;
        if (tid == 0)
            __hip_atomic_fetch_add(&ctr[(blk & 15) * 16], 1,
                                   __ATOMIC_RELAXED, __HIP_MEMORY_SCOPE_AGENT);
        if (tid < 64) {
            const int target = 256 * ph;
            for (;;) {
                int v = 0;
                if (l < 16)
                    v = __hip_atomic_load(&ctr[l * 16], __ATOMIC_RELAXED,
                                          __HIP_MEMORY_SCOPE_AGENT);
                v += __shfl_xor(v, 1, 64); v += __shfl_xor(v, 2, 64);
                v += __shfl_xor(v, 4, 64); v += __shfl_xor(v, 8, 64);
                if (__shfl(v, 0, 64) >= target) break;
                __builtin_amdgcn_s_sleep(2);
            }
        }
        __syncthreads();
        __builtin_amdgcn_fence(__ATOMIC_ACQUIRE, "agent");
    };

    // ======================= CONTEXT: P = 0..720 =======================
    for (int P = 0; P <= CTXL; ++P) {
        // lazy out-write for step P-2 (blocks 0..7, 16 samples each)
        if (blk < 8 && P >= 2) {
            const float* yp = p.Ypart + (size_t)(P & 1) * 32768;
            const int seg = tid >> 4, si2 = tid & 15;
            const int ss = blk * 16 + si2;
            float a = 0.f;
            #pragma unroll
            for (int g2 = seg * 8; g2 < seg * 8 + 8; ++g2) a += yp[g2 * 128 + ss];
            sRed[seg][si2] = a;
            __syncthreads();
            if (tid < 16) {
                const int ss2 = blk * 16 + tid;
                float yv = bheadv;
                #pragma unroll
                for (int m = 0; m < 32; ++m) yv += sRed[m][tid];
                stb(&p.out[(size_t)ss2 * OUTW + (P - 2)], yv * p.scale[ss2]);
            }
        }

        float acc0[8] = {0,0,0,0,0,0,0,0};
        float acc1[8] = {0,0,0,0,0,0,0,0};
        const float* H0p = p.H0 + (size_t)((P - 1) & 1) * HSB;  // h0(P-1)
        MM_DUAL(H0p, sW[0], sW[1], acc0, acc1);
        const float* H1p = p.H1 + (size_t)(P & 1) * HSB;        // h1(P-2)
        MM_ONE(H1p, sW[2], acc1);

        BFLY8(acc0); BFLY8(acc1);

        if (P < CTXL) {
            const float y0 = p.V[(size_t)(MAXLAG + P) * 128 + s];
            XPART(P, y0, false, acc0);
            float he[2];
            #pragma unroll
            for (int e = 0; e < 2; ++e) {
                const float ig = sigm(acc0[e * 4 + 0]), fg = sigm(acc0[e * 4 + 1]);
                const float gt = tanh_f(acc0[e * 4 + 2]), og = sigm(acc0[e * 4 + 3]);
                c0r[e] = fg * c0r[e] + ig * gt;
                he[e] = og * tanh_f(c0r[e]);
            }
            if (c == 0) {
                float* h0n = p.H0 + (size_t)(P & 1) * HSB;
                stb2(&h0n[(size_t)(blk >> 1) * 512 + s * 4 + 2 * (blk & 1)], he[0], he[1]);
            }
        }
        if (P >= 1) {
            float he[2];
            #pragma unroll
            for (int e = 0; e < 2; ++e) {
                const float ig = sigm(acc1[e * 4 + 0] + sB1[e * 4 + 0]);
                const float fg = sigm(acc1[e * 4 + 1] + sB1[e * 4 + 1]);
                const float gt = tanh_f(acc1[e * 4 + 2] + sB1[e * 4 + 2]);
                const float og = sigm(acc1[e * 4 + 3] + sB1[e * 4 + 3]);
                c1r[e] = fg * c1r[e] + ig * gt;
                he[e] = og * tanh_f(c1r[e]);
            }
            if (c == 0) {
                float* h1n = p.H1 + (size_t)((P - 1) & 1) * HSB;
                stb2(&h1n[(size_t)(blk >> 1) * 512 + s * 4 + 2 * (blk & 1)], he[0], he[1]);
                stb(&p.Ypart[(size_t)((P - 1) & 1) * 32768 + blk * 128 + s],
                    sHead[0] * he[0] + sHead[1] * he[1]);
            }
        }
        gbar();
    }

    // ======================= DECODE: t = 720..886 =======================
    for (int t = CTXL; t < NSTEP; ++t) {
        // ---- phase A: y(t-1) reduce + L0(t) ----
        {
            const float* yp = p.Ypart + (size_t)((t - 1) & 1) * 32768;
            const int seg = tid >> 7, sb = tid & 127;
            float a = 0.f;
            #pragma unroll 8
            for (int g2 = seg * 64; g2 < seg * 64 + 64; ++g2) a += yp[g2 * 128 + sb];
            sPY[seg][sb] = a;
        }
        __syncthreads();
        const float yprev = bheadv + ((sPY[0][s] + sPY[1][s]) + (sPY[2][s] + sPY[3][s]));
        if (blk < 8 && tid < 16) {
            const int ss = blk * 16 + tid;
            const float yv = bheadv + ((sPY[0][ss] + sPY[1][ss]) + (sPY[2][ss] + sPY[3][ss]));
            stb(&p.Yhat[(size_t)(t - 1) * 128 + ss], yv);
            stb(&p.out[(size_t)ss * OUTW + (t - 1)], yv * scl * 0.f + yv * p.scale[ss]);
        }
        {
            float acc0[8] = {0,0,0,0,0,0,0,0};
            const float* H0p = p.H0 + (size_t)((t - 1) & 1) * HSB;
            MM_ONE(H0p, sW[0], acc0);
            BFLY8(acc0);
            XPART(t, yprev, true, acc0);
            float he[2];
            #pragma unroll
            for (int e = 0; e < 2; ++e) {
                const float ig = sigm(acc0[e * 4 + 0]), fg = sigm(acc0[e * 4 + 1]);
                const float gt = tanh_f(acc0[e * 4 + 2]), og = sigm(acc0[e * 4 + 3]);
                c0r[e] = fg * c0r[e] + ig * gt;
                he[e] = og * tanh_f(c0r[e]);
            }
            if (c == 0) {
                float* h0n = p.H0 + (size_t)(t & 1) * HSB;
                stb2(&h0n[(size_t)(blk >> 1) * 512 + s * 4 + 2 * (blk & 1)], he[0], he[1]);
            }
        }
        gbar();

        // ---- phase B: L1(t) ----
        {
            float acc1[8] = {0,0,0,0,0,0,0,0};
            const float* H0c = p.H0 + (size_t)(t & 1) * HSB;
            MM_ONE(H0c, sW[1], acc1);
            const float* H1p = p.H1 + (size_t)((t - 1) & 1) * HSB;
            MM_ONE(H1p, sW[2], acc1);
            BFLY8(acc1);
            float he[2];
            #pragma unroll
            for (int e = 0; e < 2; ++e) {
                const float ig = sigm(acc1[e * 4 + 0] + sB1[e * 4 + 0]);
                const float fg = sigm(acc1[e * 4 + 1] + sB1[e * 4 + 1]);
                const float gt = tanh_f(acc1[e * 4 + 2] + sB1[e * 4 + 2]);
                const float og = sigm(acc1[e * 4 + 3] + sB1[e * 4 + 3]);
                c1r[e] = fg * c1r[e] + ig * gt;
                he[e] = og * tanh_f(c1r[e]);
            }
            if (c == 0) {
                float* h1n = p.H1 + (size_t)(t & 1) * HSB;
                stb2(&h1n[(size_t)(blk >> 1) * 512 + s * 4 + 2 * (blk & 1)], he[0], he[1]);
                stb(&p.Ypart[(size_t)(t & 1) * 32768 + blk * 128 + s],
                    sHead[0] * he[0] + sHead[1] * he[1]);
            }
        }
        gbar();
    }

    // ---- tail: out[:, 886] (blocks 0..7) ----
    if (blk < 8) {
        const float* yp = p.Ypart + (size_t)((NSTEP - 1) & 1) * 32768;
        const int seg = tid >> 4, si2 = tid & 15;
        const int ss = blk * 16 + si2;
        float a = 0.f;
        #pragma unroll
        for (int g2 = seg * 8; g2 < seg * 8 + 8; ++g2) a += yp[g2 * 128 + ss];
        sRed[seg][si2] = a;
        __syncthreads();
        if (tid < 16) {
            const int ss2 = blk * 16 + tid;
            float yv = bheadv;
            #pragma unroll
            for (int m = 0; m < 32; ++m) yv += sRed[m][tid];
            stb(&p.out[(size_t)ss2 * OUTW + (NSTEP - 1)], yv * p.scale[ss2]);
        }
    }
}

extern "C" void kernel_launch(void* const* d_in, const int* in_sizes, int n_in,
                              void* d_out, int out_size, void* d_ws, size_t ws_size,
                              hipStream_t stream)
{
    (void)in_sizes; (void)n_in; (void)out_size; (void)ws_size;
    const float* X   = (const float*)d_in[0];
    // d_in[1] = pad_mask (all True; see header)
    const float* emb = (const float*)d_in[2];
    Prm prm;
    prm.Wih0 = (const float*)d_in[3];
    prm.Whh0 = (const float*)d_in[4];
    prm.bih0 = (const float*)d_in[5];
    prm.bhh0 = (const float*)d_in[6];
    prm.Wih1 = (const float*)d_in[7];
    prm.Whh1 = (const float*)d_in[8];
    prm.bih1 = (const float*)d_in[9];
    prm.bhh1 = (const float*)d_in[10];
    prm.Whead = (const float*)d_in[11];
    prm.bhead = (const float*)d_in[12];
    float* out = (float*)d_out;

    float* ws    = (float*)d_ws;
    float* scale = ws;                            // 128
    float* ls    = scale + 128;                   // 128
    float* V     = ls + 128;                      // 748*128
    float* embf  = V + 748 * 128;                 // 888*5*128
    float* Yhat  = embf + (size_t)888 * 5 * 128;  // 888*128
    float* H0    = Yhat + 888 * 128;              // 2*HSB
    float* H1    = H0 + 2 * HSB;                  // 2*HSB
    float* Ypart = H1 + 2 * HSB;                  // 2*256*128
    int*   bar   = (int*)(Ypart + 2 * 256 * 128); // 256 ints

    hipLaunchKernelGGL(prep_kernel, dim3(256), dim3(256), 0, stream,
                       X, emb, scale, ls, V, embf, H0, bar);

    prm.scale = scale; prm.ls = ls; prm.V = V; prm.embf = embf;
    prm.Yhat = Yhat; prm.H0 = H0; prm.H1 = H1; prm.Ypart = Ypart; prm.out = out;
    prm.bar = bar;

    void* args[] = { &prm };
    hipLaunchCooperativeKernel((void*)deepar_persist, dim3(256), dim3(512),
                               args, 0, stream);
}